// Round 1
// baseline (1105.852 us; speedup 1.0000x reference)
//
#include <hip/hip_runtime.h>
#include <math.h>

#define D  48
#define DQ 12   // D/4

constexpr float F_EPS   = 1e-15f;
constexpr float MAXNORM = 1.0f - 1e-5f;

__device__ __forceinline__ float artanh_c(float x) {
    x = fminf(x, 1.0f - 1e-7f);
    x = fmaxf(x, -1.0f + 1e-7f);
    return atanhf(x);
}

__device__ __forceinline__ float clampabs(float x) {
    return (x >= 0.0f) ? fmaxf(x, 1e-10f) : fminf(x, -1e-10f);
}

// Per-node init: gamma, zero den, zero num accumulator (which lives in d_out).
__global__ void k_init(const float* __restrict__ x, float* __restrict__ gam,
                       float* __restrict__ den, float* __restrict__ num, int n)
{
    int i = blockIdx.x * blockDim.x + threadIdx.x;
    if (i >= n) return;
    const float4* xr = reinterpret_cast<const float4*>(x) + (size_t)i * DQ;
    float s = 0.0f;
#pragma unroll
    for (int q = 0; q < DQ; ++q) {
        float4 v = xr[q];
        s += v.x * v.x + v.y * v.y + v.z * v.z + v.w * v.w;
    }
    gam[i] = 2.0f / fmaxf(1.0f - s, F_EPS);
    den[i] = 0.0f;
    float4* nr = reinterpret_cast<float4*>(num) + (size_t)i * DQ;
    float4 z = make_float4(0.f, 0.f, 0.f, 0.f);
#pragma unroll
    for (int q = 0; q < DQ; ++q) nr[q] = z;
}

// Edge scatter: 12 threads per edge, one float4 slice each.
__global__ void k_edge(const float* __restrict__ x, const float* __restrict__ gam,
                       const int* __restrict__ src, const int* __restrict__ dst,
                       const float* __restrict__ w,
                       float* __restrict__ num, float* __restrict__ den, int E)
{
    long long t = (long long)blockIdx.x * blockDim.x + threadIdx.x;
    int e = (int)(t / DQ);
    if (e >= E) return;
    int part = (int)(t % DQ);
    int s = src[e];
    int d = dst[e];
    float we = w[e];
    float g  = gam[s];
    float4 xv = reinterpret_cast<const float4*>(x)[(size_t)s * DQ + part];
    float c = we * g;
    float* np_ = num + (size_t)d * D + part * 4;
    atomicAdd(np_ + 0, c * xv.x);
    atomicAdd(np_ + 1, c * xv.y);
    atomicAdd(np_ + 2, c * xv.z);
    atomicAdd(np_ + 3, c * xv.w);
    if (part == 0) {
        atomicAdd(den + d, fabsf(we) * (g - 1.0f));
    }
}

// mobius_scalar_mul(0.5, v) followed by _project, in place. s_in = ||v||^2.
__device__ __forceinline__ void half_mul_project(float* v)
{
    float s = 0.f;
#pragma unroll
    for (int k = 0; k < D; ++k) s += v[k] * v[k];
    float nrm = sqrtf(s);
    float ncl = fmaxf(nrm, F_EPS);
    float t   = tanhf(0.5f * artanh_c(ncl));
    float sc  = t / ncl;
    float rn  = nrm * sc;                 // norm of scaled result
    if (rn > MAXNORM) sc *= MAXNORM / fmaxf(rn, F_EPS);
#pragma unroll
    for (int k = 0; k < D; ++k) v[k] *= sc;
}

__global__ __launch_bounds__(256) void k_node(
    float* __restrict__ out,              // in: num accumulator, out: result
    const float* __restrict__ den,
    const float* __restrict__ h_init,
    const float* __restrict__ Wm,
    const float* __restrict__ bias, int n)
{
    __shared__ float Ws[D * D];
    __shared__ float bs[D];
    for (int k = threadIdx.x; k < D * D; k += blockDim.x) Ws[k] = Wm[k];
    if (threadIdx.x < D) bs[threadIdx.x] = bias[threadIdx.x];
    __syncthreads();

    int i = blockIdx.x * blockDim.x + threadIdx.x;
    if (i >= n) return;

    // ---- 1) finish weighted_midpoint_spmm: v = num/clamp_abs(den); 0.5*mul; project
    float a[D];
    {
        const float4* nr = reinterpret_cast<const float4*>(out) + (size_t)i * DQ;
        float dinv = 1.0f / clampabs(den[i]);
#pragma unroll
        for (int q = 0; q < DQ; ++q) {
            float4 v = nr[q];
            a[q * 4 + 0] = v.x * dinv;
            a[q * 4 + 1] = v.y * dinv;
            a[q * 4 + 2] = v.z * dinv;
            a[q * 4 + 3] = v.w * dinv;
        }
    }
    half_mul_project(a);

    // ---- 2) weighted_midpoint_pair(a, h_init, 0.9, 0.1)
    {
        float b[D];
        const float4* hr = reinterpret_cast<const float4*>(h_init) + (size_t)i * DQ;
#pragma unroll
        for (int q = 0; q < DQ; ++q) {
            float4 v = hr[q];
            b[q * 4 + 0] = v.x; b[q * 4 + 1] = v.y;
            b[q * 4 + 2] = v.z; b[q * 4 + 3] = v.w;
        }
        float sa = 0.f, sb = 0.f;
#pragma unroll
        for (int k = 0; k < D; ++k) { sa += a[k] * a[k]; sb += b[k] * b[k]; }
        float ga = 2.0f / fmaxf(1.0f - sa, F_EPS);
        float gb = 2.0f / fmaxf(1.0f - sb, F_EPS);
        const float wa = 0.9f, wb = 0.1f;
        float dinv = 1.0f / clampabs(wa * (ga - 1.0f) + wb * (gb - 1.0f));
        float ca = wa * ga * dinv, cb = wb * gb * dinv;
#pragma unroll
        for (int k = 0; k < D; ++k) a[k] = ca * a[k] + cb * b[k];
        half_mul_project(a);
    }

    // ---- 3) mobius_matvec(W, a): mx = a @ W^T, tanh rescale, project
    float mx[D];
    {
        float sa2 = 0.f;
#pragma unroll
        for (int k = 0; k < D; ++k) sa2 += a[k] * a[k];
        float xn = fmaxf(sqrtf(sa2), F_EPS);
        float smx = 0.f;
        for (int j = 0; j < D; ++j) {
            float acc = 0.f;
#pragma unroll
            for (int k = 0; k < D; ++k) acc = fmaf(Ws[j * D + k], a[k], acc);
            mx[j] = acc;
            smx += acc * acc;
        }
        float mxnr = sqrtf(smx);
        float mxn = fmaxf(mxnr, F_EPS);
        float tt = tanhf(mxnr >= F_EPS ? (mxn / xn) * artanh_c(xn)
                                       : (mxn / xn) * artanh_c(xn));
        float sc = tt / mxn;
        float rn = mxnr * sc;
        if (rn > MAXNORM) sc *= MAXNORM / fmaxf(rn, F_EPS);
#pragma unroll
        for (int j = 0; j < D; ++j) mx[j] *= sc;
    }

    // ---- 4) mobius_add(mx, expmap0(bias)), project, store
    {
        float bn2 = 0.f;
#pragma unroll
        for (int k = 0; k < D; ++k) bn2 += bs[k] * bs[k];
        float bn  = fmaxf(sqrtf(bn2), F_EPS);
        float tb  = tanhf(bn);
        float ebs = tb / bn;              // eb[k] = ebs * bs[k]
        float y2  = ebs * ebs * bn2;      // ||eb||^2

        float x2 = 0.f, xy = 0.f;
#pragma unroll
        for (int k = 0; k < D; ++k) { x2 += mx[k] * mx[k]; xy += mx[k] * bs[k]; }
        xy *= ebs;

        float c1 = 1.0f + 2.0f * xy + y2;
        float c2 = 1.0f - x2;
        float dn3 = 1.0f / fmaxf(1.0f + 2.0f * xy + x2 * y2, F_EPS);

        float r[D];
        float s3 = 0.f;
#pragma unroll
        for (int k = 0; k < D; ++k) {
            float rv = (c1 * mx[k] + c2 * ebs * bs[k]) * dn3;
            r[k] = rv;
            s3 += rv * rv;
        }
        float nrm3 = sqrtf(s3);
        float fp = 1.0f;
        if (nrm3 > MAXNORM) fp = MAXNORM / fmaxf(nrm3, F_EPS);

        float4* orow = reinterpret_cast<float4*>(out) + (size_t)i * DQ;
#pragma unroll
        for (int q = 0; q < DQ; ++q) {
            float4 v;
            v.x = r[q * 4 + 0] * fp;
            v.y = r[q * 4 + 1] * fp;
            v.z = r[q * 4 + 2] * fp;
            v.w = r[q * 4 + 3] * fp;
            orow[q] = v;
        }
    }
}

extern "C" void kernel_launch(void* const* d_in, const int* in_sizes, int n_in,
                              void* d_out, int out_size, void* d_ws, size_t ws_size,
                              hipStream_t stream)
{
    const float* x      = (const float*)d_in[0];
    const float* h_init = (const float*)d_in[1];
    const float* edge_w = (const float*)d_in[2];
    const float* W      = (const float*)d_in[3];
    const float* bias   = (const float*)d_in[4];
    const int*   esrc   = (const int*)d_in[5];
    const int*   edst   = (const int*)d_in[6];
    float* out = (float*)d_out;

    int n = in_sizes[0] / D;
    int E = in_sizes[2];

    float* gam = (float*)d_ws;        // [n]
    float* den = gam + n;             // [n]

    k_init<<<(n + 255) / 256, 256, 0, stream>>>(x, gam, den, out, n);

    long long tot = (long long)E * DQ;
    int grid = (int)((tot + 255) / 256);
    k_edge<<<grid, 256, 0, stream>>>(x, gam, esrc, edst, edge_w, out, den, E);

    k_node<<<(n + 255) / 256, 256, 0, stream>>>(out, den, h_init, W, bias, n);
}

// Round 2
// 305.544 us; speedup vs baseline: 3.6193x; 3.6193x over previous
//
#include <hip/hip_runtime.h>
#include <math.h>

#define D  48
#define DQ 12   // D/4
#define CHUNK 2048   // elements per scan block (256 thr x 8)

constexpr float F_EPS   = 1e-15f;
constexpr float MAXNORM = 1.0f - 1e-5f;

__device__ __forceinline__ float artanh_c(float x) {
    x = fminf(x, 1.0f - 1e-7f);
    x = fmaxf(x, -1.0f + 1e-7f);
    return atanhf(x);
}

__device__ __forceinline__ float clampabs(float x) {
    return (x >= 0.0f) ? fmaxf(x, 1e-10f) : fminf(x, -1e-10f);
}

// ---------- per-node gamma ----------
__global__ void k_gamma(const float* __restrict__ x, float* __restrict__ gam, int n)
{
    int i = blockIdx.x * blockDim.x + threadIdx.x;
    if (i >= n) return;
    const float4* xr = reinterpret_cast<const float4*>(x) + (size_t)i * DQ;
    float s = 0.0f;
#pragma unroll
    for (int q = 0; q < DQ; ++q) {
        float4 v = xr[q];
        s += v.x * v.x + v.y * v.y + v.z * v.z + v.w * v.w;
    }
    gam[i] = 2.0f / fmaxf(1.0f - s, F_EPS);
}

// ---------- CSR build: histogram of dst ----------
__global__ void k_count(const int* __restrict__ dst, int* __restrict__ counts, int E)
{
    int i = blockIdx.x * blockDim.x + threadIdx.x;
    if (i >= E) return;
    atomicAdd(&counts[dst[i]], 1);
}

// ---------- scan pass 1: per-block sums of counts ----------
__global__ __launch_bounds__(256) void k_scan1(const int* __restrict__ counts,
                                               int* __restrict__ bsums, int n)
{
    __shared__ int sh[256];
    int base = blockIdx.x * CHUNK + threadIdx.x * 8;
    int s = 0;
#pragma unroll
    for (int k = 0; k < 8; ++k) {
        int i = base + k;
        if (i < n) s += counts[i];
    }
    sh[threadIdx.x] = s;
    __syncthreads();
    for (int off = 128; off > 0; off >>= 1) {
        if (threadIdx.x < off) sh[threadIdx.x] += sh[threadIdx.x + off];
        __syncthreads();
    }
    if (threadIdx.x == 0) bsums[blockIdx.x] = sh[0];
}

// ---------- scan pass 2: exclusive scan of block sums (single block) ----------
__global__ __launch_bounds__(256) void k_scan2(int* __restrict__ bsums,
                                               int* __restrict__ bscan,
                                               int* __restrict__ starts,
                                               int nb, int n)
{
    __shared__ int sh[256];
    int t = threadIdx.x;
    int v = (t < nb) ? bsums[t] : 0;
    sh[t] = v;
    __syncthreads();
    for (int off = 1; off < 256; off <<= 1) {
        int a = sh[t];
        int b = (t >= off) ? sh[t - off] : 0;
        __syncthreads();
        sh[t] = a + b;
        __syncthreads();
    }
    if (t < nb) bscan[t] = sh[t] - v;   // exclusive
    if (t == 255) starts[n] = sh[255];  // total = E
}

// ---------- scan pass 3: local scan + offset -> starts, cursor ----------
__global__ __launch_bounds__(256) void k_scan3(const int* __restrict__ counts,
                                               const int* __restrict__ bscan,
                                               int* __restrict__ starts,
                                               int* __restrict__ cursor, int n)
{
    __shared__ int sh[256];
    int base = blockIdx.x * CHUNK + threadIdx.x * 8;
    int v[8];
    int s = 0;
#pragma unroll
    for (int k = 0; k < 8; ++k) {
        int i = base + k;
        v[k] = (i < n) ? counts[i] : 0;
        s += v[k];
    }
    sh[threadIdx.x] = s;
    __syncthreads();
    for (int off = 1; off < 256; off <<= 1) {
        int a = sh[threadIdx.x];
        int b = (threadIdx.x >= off) ? sh[threadIdx.x - off] : 0;
        __syncthreads();
        sh[threadIdx.x] = a + b;
        __syncthreads();
    }
    int run = bscan[blockIdx.x] + sh[threadIdx.x] - s;  // exclusive offset of this thread's chunk
#pragma unroll
    for (int k = 0; k < 8; ++k) {
        int i = base + k;
        if (i < n) { starts[i] = run; cursor[i] = run; }
        run += v[k];
    }
}

// ---------- scatter edges into dst-sorted order ----------
__global__ void k_scatter(const int* __restrict__ src, const int* __restrict__ dst,
                          const float* __restrict__ w,
                          int* __restrict__ cursor,
                          int* __restrict__ ssrc, float* __restrict__ sw, int E)
{
    int i = blockIdx.x * blockDim.x + threadIdx.x;
    if (i >= E) return;
    int d = dst[i];
    int pos = atomicAdd(&cursor[d], 1);
    ssrc[pos] = src[i];
    sw[pos] = w[i];
}

// ---------- gather-side segment reduction: 12 lanes per node ----------
__global__ __launch_bounds__(256) void k_gather(
    const float* __restrict__ x, const float* __restrict__ gam,
    const int* __restrict__ starts,
    const int* __restrict__ ssrc, const float* __restrict__ sw,
    float* __restrict__ num, float* __restrict__ den, int n)
{
    long long t = (long long)blockIdx.x * blockDim.x + threadIdx.x;
    int node = (int)(t / DQ);
    if (node >= n) return;
    int part = (int)(t % DQ);
    int j0 = starts[node], j1 = starts[node + 1];
    const float4* x4 = reinterpret_cast<const float4*>(x);
    float4 acc = make_float4(0.f, 0.f, 0.f, 0.f);
    float dacc = 0.f;
    for (int j = j0; j < j1; ++j) {
        int s   = ssrc[j];
        float wv = sw[j];
        float g  = gam[s];
        float4 xv = x4[(size_t)s * DQ + part];
        float c = wv * g;
        acc.x = fmaf(c, xv.x, acc.x);
        acc.y = fmaf(c, xv.y, acc.y);
        acc.z = fmaf(c, xv.z, acc.z);
        acc.w = fmaf(c, xv.w, acc.w);
        dacc += fabsf(wv) * (g - 1.0f);
    }
    reinterpret_cast<float4*>(num)[(size_t)node * DQ + part] = acc;
    if (part == 0) den[node] = dacc;
}

// ---------- fallback atomic edge scatter (if ws too small) ----------
__global__ void k_init_atomic(float* __restrict__ den, float* __restrict__ num, int n)
{
    int i = blockIdx.x * blockDim.x + threadIdx.x;
    if (i >= n) return;
    den[i] = 0.0f;
    float4* nr = reinterpret_cast<float4*>(num) + (size_t)i * DQ;
    float4 z = make_float4(0.f, 0.f, 0.f, 0.f);
#pragma unroll
    for (int q = 0; q < DQ; ++q) nr[q] = z;
}

__global__ void k_edge_atomic(const float* __restrict__ x, const float* __restrict__ gam,
                              const int* __restrict__ src, const int* __restrict__ dst,
                              const float* __restrict__ w,
                              float* __restrict__ num, float* __restrict__ den, int E)
{
    long long t = (long long)blockIdx.x * blockDim.x + threadIdx.x;
    int e = (int)(t / DQ);
    if (e >= E) return;
    int part = (int)(t % DQ);
    int s = src[e];
    int d = dst[e];
    float we = w[e];
    float g  = gam[s];
    float4 xv = reinterpret_cast<const float4*>(x)[(size_t)s * DQ + part];
    float c = we * g;
    float* np_ = num + (size_t)d * D + part * 4;
    atomicAdd(np_ + 0, c * xv.x);
    atomicAdd(np_ + 1, c * xv.y);
    atomicAdd(np_ + 2, c * xv.z);
    atomicAdd(np_ + 3, c * xv.w);
    if (part == 0) atomicAdd(den + d, fabsf(we) * (g - 1.0f));
}

// mobius_scalar_mul(0.5, v) followed by _project, in place.
__device__ __forceinline__ void half_mul_project(float* v)
{
    float s = 0.f;
#pragma unroll
    for (int k = 0; k < D; ++k) s += v[k] * v[k];
    float nrm = sqrtf(s);
    float ncl = fmaxf(nrm, F_EPS);
    float t   = tanhf(0.5f * artanh_c(ncl));
    float sc  = t / ncl;
    float rn  = nrm * sc;
    if (rn > MAXNORM) sc *= MAXNORM / fmaxf(rn, F_EPS);
#pragma unroll
    for (int k = 0; k < D; ++k) v[k] *= sc;
}

__global__ __launch_bounds__(256) void k_node(
    float* __restrict__ out,              // in: num accumulator, out: result
    const float* __restrict__ den,
    const float* __restrict__ h_init,
    const float* __restrict__ Wm,
    const float* __restrict__ bias, int n)
{
    __shared__ float Ws[D * D];
    __shared__ float bs[D];
    for (int k = threadIdx.x; k < D * D; k += blockDim.x) Ws[k] = Wm[k];
    if (threadIdx.x < D) bs[threadIdx.x] = bias[threadIdx.x];
    __syncthreads();

    int i = blockIdx.x * blockDim.x + threadIdx.x;
    if (i >= n) return;

    // ---- 1) finish weighted_midpoint_spmm
    float a[D];
    {
        const float4* nr = reinterpret_cast<const float4*>(out) + (size_t)i * DQ;
        float dinv = 1.0f / clampabs(den[i]);
#pragma unroll
        for (int q = 0; q < DQ; ++q) {
            float4 v = nr[q];
            a[q * 4 + 0] = v.x * dinv;
            a[q * 4 + 1] = v.y * dinv;
            a[q * 4 + 2] = v.z * dinv;
            a[q * 4 + 3] = v.w * dinv;
        }
    }
    half_mul_project(a);

    // ---- 2) weighted_midpoint_pair(a, h_init, 0.9, 0.1)
    {
        float b[D];
        const float4* hr = reinterpret_cast<const float4*>(h_init) + (size_t)i * DQ;
#pragma unroll
        for (int q = 0; q < DQ; ++q) {
            float4 v = hr[q];
            b[q * 4 + 0] = v.x; b[q * 4 + 1] = v.y;
            b[q * 4 + 2] = v.z; b[q * 4 + 3] = v.w;
        }
        float sa = 0.f, sb = 0.f;
#pragma unroll
        for (int k = 0; k < D; ++k) { sa += a[k] * a[k]; sb += b[k] * b[k]; }
        float ga = 2.0f / fmaxf(1.0f - sa, F_EPS);
        float gb = 2.0f / fmaxf(1.0f - sb, F_EPS);
        const float wa = 0.9f, wb = 0.1f;
        float dinv = 1.0f / clampabs(wa * (ga - 1.0f) + wb * (gb - 1.0f));
        float ca = wa * ga * dinv, cb = wb * gb * dinv;
#pragma unroll
        for (int k = 0; k < D; ++k) a[k] = ca * a[k] + cb * b[k];
        half_mul_project(a);
    }

    // ---- 3) mobius_matvec(W, a)
    float mx[D];
    {
        float sa2 = 0.f;
#pragma unroll
        for (int k = 0; k < D; ++k) sa2 += a[k] * a[k];
        float xn = fmaxf(sqrtf(sa2), F_EPS);
        float smx = 0.f;
        for (int j = 0; j < D; ++j) {
            float acc = 0.f;
#pragma unroll
            for (int k = 0; k < D; ++k) acc = fmaf(Ws[j * D + k], a[k], acc);
            mx[j] = acc;
            smx += acc * acc;
        }
        float mxnr = sqrtf(smx);
        float mxn = fmaxf(mxnr, F_EPS);
        float tt = tanhf((mxn / xn) * artanh_c(xn));
        float sc = tt / mxn;
        float rn = mxnr * sc;
        if (rn > MAXNORM) sc *= MAXNORM / fmaxf(rn, F_EPS);
#pragma unroll
        for (int j = 0; j < D; ++j) mx[j] *= sc;
    }

    // ---- 4) mobius_add(mx, expmap0(bias)), project, store
    {
        float bn2 = 0.f;
#pragma unroll
        for (int k = 0; k < D; ++k) bn2 += bs[k] * bs[k];
        float bn  = fmaxf(sqrtf(bn2), F_EPS);
        float tb  = tanhf(bn);
        float ebs = tb / bn;
        float y2  = ebs * ebs * bn2;

        float x2 = 0.f, xy = 0.f;
#pragma unroll
        for (int k = 0; k < D; ++k) { x2 += mx[k] * mx[k]; xy += mx[k] * bs[k]; }
        xy *= ebs;

        float c1 = 1.0f + 2.0f * xy + y2;
        float c2 = 1.0f - x2;
        float dn3 = 1.0f / fmaxf(1.0f + 2.0f * xy + x2 * y2, F_EPS);

        float r[D];
        float s3 = 0.f;
#pragma unroll
        for (int k = 0; k < D; ++k) {
            float rv = (c1 * mx[k] + c2 * ebs * bs[k]) * dn3;
            r[k] = rv;
            s3 += rv * rv;
        }
        float nrm3 = sqrtf(s3);
        float fp = 1.0f;
        if (nrm3 > MAXNORM) fp = MAXNORM / fmaxf(nrm3, F_EPS);

        float4* orow = reinterpret_cast<float4*>(out) + (size_t)i * DQ;
#pragma unroll
        for (int q = 0; q < DQ; ++q) {
            float4 v;
            v.x = r[q * 4 + 0] * fp;
            v.y = r[q * 4 + 1] * fp;
            v.z = r[q * 4 + 2] * fp;
            v.w = r[q * 4 + 3] * fp;
            orow[q] = v;
        }
    }
}

extern "C" void kernel_launch(void* const* d_in, const int* in_sizes, int n_in,
                              void* d_out, int out_size, void* d_ws, size_t ws_size,
                              hipStream_t stream)
{
    const float* x      = (const float*)d_in[0];
    const float* h_init = (const float*)d_in[1];
    const float* edge_w = (const float*)d_in[2];
    const float* W      = (const float*)d_in[3];
    const float* bias   = (const float*)d_in[4];
    const int*   esrc   = (const int*)d_in[5];
    const int*   edst   = (const int*)d_in[6];
    float* out = (float*)d_out;

    int n = in_sizes[0] / D;
    int E = in_sizes[2];
    int nb = (n + CHUNK - 1) / CHUNK;

    // ws layout
    char* p = (char*)d_ws;
    float* gam    = (float*)p;             p += (size_t)n * 4;
    float* den    = (float*)p;             p += (size_t)n * 4;
    int*   counts = (int*)p;               p += (size_t)n * 4;
    int*   starts = (int*)p;               p += (size_t)(n + 1) * 4;
    int*   cursor = (int*)p;               p += (size_t)n * 4;
    int*   bsums  = (int*)p;               p += (size_t)nb * 4;
    int*   bscan  = (int*)p;               p += (size_t)nb * 4;
    int*   ssrc   = (int*)p;               p += (size_t)E * 4;
    float* sw     = (float*)p;             p += (size_t)E * 4;
    size_t needed = (size_t)(p - (char*)d_ws);

    k_gamma<<<(n + 255) / 256, 256, 0, stream>>>(x, gam, n);

    bool csr_ok = (needed <= ws_size) && (nb <= 256);
    if (csr_ok) {
        hipMemsetAsync(counts, 0, (size_t)n * 4, stream);
        k_count<<<(E + 255) / 256, 256, 0, stream>>>(edst, counts, E);
        k_scan1<<<nb, 256, 0, stream>>>(counts, bsums, n);
        k_scan2<<<1, 256, 0, stream>>>(bsums, bscan, starts, nb, n);
        k_scan3<<<nb, 256, 0, stream>>>(counts, bscan, starts, cursor, n);
        k_scatter<<<(E + 255) / 256, 256, 0, stream>>>(esrc, edst, edge_w, cursor, ssrc, sw, E);
        long long tot = (long long)n * DQ;
        k_gather<<<(int)((tot + 255) / 256), 256, 0, stream>>>(x, gam, starts, ssrc, sw, out, den, n);
    } else {
        k_init_atomic<<<(n + 255) / 256, 256, 0, stream>>>(den, out, n);
        long long tot = (long long)E * DQ;
        k_edge_atomic<<<(int)((tot + 255) / 256), 256, 0, stream>>>(x, gam, esrc, edst, edge_w, out, den, E);
    }

    k_node<<<(n + 255) / 256, 256, 0, stream>>>(out, den, h_init, W, bias, n);
}

// Round 3
// 297.523 us; speedup vs baseline: 3.7169x; 1.0270x over previous
//
#include <hip/hip_runtime.h>
#include <math.h>

#define D  48
#define DQ 12   // D/4
#define CHUNK 2048   // elements per scan block (256 thr x 8)

constexpr float F_EPS   = 1e-15f;
constexpr float MAXNORM = 1.0f - 1e-5f;

__device__ __forceinline__ float artanh_c(float x) {
    x = fminf(x, 1.0f - 1e-7f);
    x = fmaxf(x, -1.0f + 1e-7f);
    return atanhf(x);
}

__device__ __forceinline__ float clampabs(float x) {
    return (x >= 0.0f) ? fmaxf(x, 1e-10f) : fminf(x, -1e-10f);
}

// ---------- per-node gamma + zero counts ----------
__global__ void k_gamma(const float* __restrict__ x, float* __restrict__ gam,
                        int* __restrict__ counts, int n)
{
    int i = blockIdx.x * blockDim.x + threadIdx.x;
    if (i >= n) return;
    const float4* xr = reinterpret_cast<const float4*>(x) + (size_t)i * DQ;
    float s = 0.0f;
#pragma unroll
    for (int q = 0; q < DQ; ++q) {
        float4 v = xr[q];
        s += v.x * v.x + v.y * v.y + v.z * v.z + v.w * v.w;
    }
    gam[i] = 2.0f / fmaxf(1.0f - s, F_EPS);
    counts[i] = 0;
}

// ---------- CSR build: histogram of dst ----------
__global__ void k_count(const int* __restrict__ dst, int* __restrict__ counts, int E)
{
    int i = blockIdx.x * blockDim.x + threadIdx.x;
    if (i >= E) return;
    atomicAdd(&counts[dst[i]], 1);
}

// ---------- scan pass 1: per-block sums of counts ----------
__global__ __launch_bounds__(256) void k_scan1(const int* __restrict__ counts,
                                               int* __restrict__ bsums, int n)
{
    __shared__ int sh[256];
    int base = blockIdx.x * CHUNK + threadIdx.x * 8;
    int s = 0;
#pragma unroll
    for (int k = 0; k < 8; ++k) {
        int i = base + k;
        if (i < n) s += counts[i];
    }
    sh[threadIdx.x] = s;
    __syncthreads();
    for (int off = 128; off > 0; off >>= 1) {
        if (threadIdx.x < off) sh[threadIdx.x] += sh[threadIdx.x + off];
        __syncthreads();
    }
    if (threadIdx.x == 0) bsums[blockIdx.x] = sh[0];
}

// ---------- scan pass 2: exclusive scan of block sums (single block) ----------
__global__ __launch_bounds__(256) void k_scan2(int* __restrict__ bsums,
                                               int* __restrict__ bscan,
                                               int* __restrict__ starts,
                                               int nb, int n)
{
    __shared__ int sh[256];
    int t = threadIdx.x;
    int v = (t < nb) ? bsums[t] : 0;
    sh[t] = v;
    __syncthreads();
    for (int off = 1; off < 256; off <<= 1) {
        int a = sh[t];
        int b = (t >= off) ? sh[t - off] : 0;
        __syncthreads();
        sh[t] = a + b;
        __syncthreads();
    }
    if (t < nb) bscan[t] = sh[t] - v;   // exclusive
    if (t == 255) starts[n] = sh[255];  // total = E
}

// ---------- scan pass 3: local scan + offset -> starts, cursor ----------
__global__ __launch_bounds__(256) void k_scan3(const int* __restrict__ counts,
                                               const int* __restrict__ bscan,
                                               int* __restrict__ starts,
                                               int* __restrict__ cursor, int n)
{
    __shared__ int sh[256];
    int base = blockIdx.x * CHUNK + threadIdx.x * 8;
    int v[8];
    int s = 0;
#pragma unroll
    for (int k = 0; k < 8; ++k) {
        int i = base + k;
        v[k] = (i < n) ? counts[i] : 0;
        s += v[k];
    }
    sh[threadIdx.x] = s;
    __syncthreads();
    for (int off = 1; off < 256; off <<= 1) {
        int a = sh[threadIdx.x];
        int b = (threadIdx.x >= off) ? sh[threadIdx.x - off] : 0;
        __syncthreads();
        sh[threadIdx.x] = a + b;
        __syncthreads();
    }
    int run = bscan[blockIdx.x] + sh[threadIdx.x] - s;
#pragma unroll
    for (int k = 0; k < 8; ++k) {
        int i = base + k;
        if (i < n) { starts[i] = run; cursor[i] = run; }
        run += v[k];
    }
}

// ---------- scatter edges into dst-sorted order: one 8B record per edge ----------
__global__ void k_scatter(const int* __restrict__ src, const int* __restrict__ dst,
                          const float* __restrict__ w,
                          int* __restrict__ cursor,
                          int2* __restrict__ srec, int E)
{
    int i = blockIdx.x * blockDim.x + threadIdx.x;
    if (i >= E) return;
    int d = dst[i];
    int pos = atomicAdd(&cursor[d], 1);
    int2 rec;
    rec.x = src[i];
    rec.y = __float_as_int(w[i]);
    srec[pos] = rec;
}

// ---------- gather-side segment reduction: 12 lanes per node ----------
__global__ __launch_bounds__(256) void k_gather(
    const float* __restrict__ x, const float* __restrict__ gam,
    const int* __restrict__ starts,
    const int2* __restrict__ srec,
    float* __restrict__ num, float* __restrict__ den, int n)
{
    long long t = (long long)blockIdx.x * blockDim.x + threadIdx.x;
    int node = (int)(t / DQ);
    if (node >= n) return;
    int part = (int)(t % DQ);
    int j0 = starts[node], j1 = starts[node + 1];
    const float4* x4 = reinterpret_cast<const float4*>(x);
    float4 acc = make_float4(0.f, 0.f, 0.f, 0.f);
    float dacc = 0.f;
    for (int j = j0; j < j1; ++j) {
        int2 rec = srec[j];
        int s    = rec.x;
        float wv = __int_as_float(rec.y);
        float g  = gam[s];
        float4 xv = x4[(size_t)s * DQ + part];
        float c = wv * g;
        acc.x = fmaf(c, xv.x, acc.x);
        acc.y = fmaf(c, xv.y, acc.y);
        acc.z = fmaf(c, xv.z, acc.z);
        acc.w = fmaf(c, xv.w, acc.w);
        dacc += fabsf(wv) * (g - 1.0f);
    }
    reinterpret_cast<float4*>(num)[(size_t)node * DQ + part] = acc;
    if (part == 0) den[node] = dacc;
}

// ---------- fallback atomic edge scatter (if ws too small) ----------
__global__ void k_init_atomic(float* __restrict__ den, float* __restrict__ num, int n)
{
    int i = blockIdx.x * blockDim.x + threadIdx.x;
    if (i >= n) return;
    den[i] = 0.0f;
    float4* nr = reinterpret_cast<float4*>(num) + (size_t)i * DQ;
    float4 z = make_float4(0.f, 0.f, 0.f, 0.f);
#pragma unroll
    for (int q = 0; q < DQ; ++q) nr[q] = z;
}

__global__ void k_edge_atomic(const float* __restrict__ x, const float* __restrict__ gam,
                              const int* __restrict__ src, const int* __restrict__ dst,
                              const float* __restrict__ w,
                              float* __restrict__ num, float* __restrict__ den, int E)
{
    long long t = (long long)blockIdx.x * blockDim.x + threadIdx.x;
    int e = (int)(t / DQ);
    if (e >= E) return;
    int part = (int)(t % DQ);
    int s = src[e];
    int d = dst[e];
    float we = w[e];
    float g  = gam[s];
    float4 xv = reinterpret_cast<const float4*>(x)[(size_t)s * DQ + part];
    float c = we * g;
    float* np_ = num + (size_t)d * D + part * 4;
    atomicAdd(np_ + 0, c * xv.x);
    atomicAdd(np_ + 1, c * xv.y);
    atomicAdd(np_ + 2, c * xv.z);
    atomicAdd(np_ + 3, c * xv.w);
    if (part == 0) atomicAdd(den + d, fabsf(we) * (g - 1.0f));
}

// mobius_scalar_mul(0.5, v) followed by _project, in place.
__device__ __forceinline__ void half_mul_project(float* v)
{
    float s = 0.f;
#pragma unroll
    for (int k = 0; k < D; ++k) s += v[k] * v[k];
    float nrm = sqrtf(s);
    float ncl = fmaxf(nrm, F_EPS);
    float t   = tanhf(0.5f * artanh_c(ncl));
    float sc  = t / ncl;
    float rn  = nrm * sc;
    if (rn > MAXNORM) sc *= MAXNORM / fmaxf(rn, F_EPS);
#pragma unroll
    for (int k = 0; k < D; ++k) v[k] *= sc;
}

__global__ __launch_bounds__(256) void k_node(
    float* __restrict__ out,              // in: num accumulator, out: result
    const float* __restrict__ den,
    const float* __restrict__ h_init,
    const float* __restrict__ Wm,
    const float* __restrict__ bias, int n)
{
    __shared__ float Ws[D * D];
    __shared__ float bs[D];
    for (int k = threadIdx.x; k < D * D; k += blockDim.x) Ws[k] = Wm[k];
    if (threadIdx.x < D) bs[threadIdx.x] = bias[threadIdx.x];
    __syncthreads();

    int i = blockIdx.x * blockDim.x + threadIdx.x;
    if (i >= n) return;

    // ---- 1) finish weighted_midpoint_spmm
    float a[D];
    {
        const float4* nr = reinterpret_cast<const float4*>(out) + (size_t)i * DQ;
        float dinv = 1.0f / clampabs(den[i]);
#pragma unroll
        for (int q = 0; q < DQ; ++q) {
            float4 v = nr[q];
            a[q * 4 + 0] = v.x * dinv;
            a[q * 4 + 1] = v.y * dinv;
            a[q * 4 + 2] = v.z * dinv;
            a[q * 4 + 3] = v.w * dinv;
        }
    }
    half_mul_project(a);

    // ---- 2) weighted_midpoint_pair(a, h_init, 0.9, 0.1)
    {
        float b[D];
        const float4* hr = reinterpret_cast<const float4*>(h_init) + (size_t)i * DQ;
#pragma unroll
        for (int q = 0; q < DQ; ++q) {
            float4 v = hr[q];
            b[q * 4 + 0] = v.x; b[q * 4 + 1] = v.y;
            b[q * 4 + 2] = v.z; b[q * 4 + 3] = v.w;
        }
        float sa = 0.f, sb = 0.f;
#pragma unroll
        for (int k = 0; k < D; ++k) { sa += a[k] * a[k]; sb += b[k] * b[k]; }
        float ga = 2.0f / fmaxf(1.0f - sa, F_EPS);
        float gb = 2.0f / fmaxf(1.0f - sb, F_EPS);
        const float wa = 0.9f, wb = 0.1f;
        float dinv = 1.0f / clampabs(wa * (ga - 1.0f) + wb * (gb - 1.0f));
        float ca = wa * ga * dinv, cb = wb * gb * dinv;
#pragma unroll
        for (int k = 0; k < D; ++k) a[k] = ca * a[k] + cb * b[k];
        half_mul_project(a);
    }

    // ---- 3) mobius_matvec(W, a)
    float mx[D];
    {
        float sa2 = 0.f;
#pragma unroll
        for (int k = 0; k < D; ++k) sa2 += a[k] * a[k];
        float xn = fmaxf(sqrtf(sa2), F_EPS);
        float smx = 0.f;
        for (int j = 0; j < D; ++j) {
            float acc = 0.f;
#pragma unroll
            for (int k = 0; k < D; ++k) acc = fmaf(Ws[j * D + k], a[k], acc);
            mx[j] = acc;
            smx += acc * acc;
        }
        float mxnr = sqrtf(smx);
        float mxn = fmaxf(mxnr, F_EPS);
        float tt = tanhf((mxn / xn) * artanh_c(xn));
        float sc = tt / mxn;
        float rn = mxnr * sc;
        if (rn > MAXNORM) sc *= MAXNORM / fmaxf(rn, F_EPS);
#pragma unroll
        for (int j = 0; j < D; ++j) mx[j] *= sc;
    }

    // ---- 4) mobius_add(mx, expmap0(bias)), project, store
    {
        float bn2 = 0.f;
#pragma unroll
        for (int k = 0; k < D; ++k) bn2 += bs[k] * bs[k];
        float bn  = fmaxf(sqrtf(bn2), F_EPS);
        float tb  = tanhf(bn);
        float ebs = tb / bn;
        float y2  = ebs * ebs * bn2;

        float x2 = 0.f, xy = 0.f;
#pragma unroll
        for (int k = 0; k < D; ++k) { x2 += mx[k] * mx[k]; xy += mx[k] * bs[k]; }
        xy *= ebs;

        float c1 = 1.0f + 2.0f * xy + y2;
        float c2 = 1.0f - x2;
        float dn3 = 1.0f / fmaxf(1.0f + 2.0f * xy + x2 * y2, F_EPS);

        float r[D];
        float s3 = 0.f;
#pragma unroll
        for (int k = 0; k < D; ++k) {
            float rv = (c1 * mx[k] + c2 * ebs * bs[k]) * dn3;
            r[k] = rv;
            s3 += rv * rv;
        }
        float nrm3 = sqrtf(s3);
        float fp = 1.0f;
        if (nrm3 > MAXNORM) fp = MAXNORM / fmaxf(nrm3, F_EPS);

        float4* orow = reinterpret_cast<float4*>(out) + (size_t)i * DQ;
#pragma unroll
        for (int q = 0; q < DQ; ++q) {
            float4 v;
            v.x = r[q * 4 + 0] * fp;
            v.y = r[q * 4 + 1] * fp;
            v.z = r[q * 4 + 2] * fp;
            v.w = r[q * 4 + 3] * fp;
            orow[q] = v;
        }
    }
}

extern "C" void kernel_launch(void* const* d_in, const int* in_sizes, int n_in,
                              void* d_out, int out_size, void* d_ws, size_t ws_size,
                              hipStream_t stream)
{
    const float* x      = (const float*)d_in[0];
    const float* h_init = (const float*)d_in[1];
    const float* edge_w = (const float*)d_in[2];
    const float* W      = (const float*)d_in[3];
    const float* bias   = (const float*)d_in[4];
    const int*   esrc   = (const int*)d_in[5];
    const int*   edst   = (const int*)d_in[6];
    float* out = (float*)d_out;

    int n = in_sizes[0] / D;
    int E = in_sizes[2];
    int nb = (n + CHUNK - 1) / CHUNK;

    // ws layout
    char* p = (char*)d_ws;
    float* gam    = (float*)p;             p += (size_t)n * 4;
    float* den    = (float*)p;             p += (size_t)n * 4;
    int*   counts = (int*)p;               p += (size_t)n * 4;
    int*   starts = (int*)p;               p += (size_t)(n + 1) * 4;
    int*   cursor = (int*)p;               p += (size_t)n * 4;
    int*   bsums  = (int*)p;               p += (size_t)nb * 4;
    int*   bscan  = (int*)p;               p += (size_t)nb * 4;
    p = (char*)(((uintptr_t)p + 15) & ~(uintptr_t)15);   // align 16
    int2*  srec   = (int2*)p;              p += (size_t)E * 8;
    size_t needed = (size_t)(p - (char*)d_ws);

    k_gamma<<<(n + 255) / 256, 256, 0, stream>>>(x, gam, counts, n);

    bool csr_ok = (needed <= ws_size) && (nb <= 256);
    if (csr_ok) {
        k_count<<<(E + 255) / 256, 256, 0, stream>>>(edst, counts, E);
        k_scan1<<<nb, 256, 0, stream>>>(counts, bsums, n);
        k_scan2<<<1, 256, 0, stream>>>(bsums, bscan, starts, nb, n);
        k_scan3<<<nb, 256, 0, stream>>>(counts, bscan, starts, cursor, n);
        k_scatter<<<(E + 255) / 256, 256, 0, stream>>>(esrc, edst, edge_w, cursor, srec, E);
        long long tot = (long long)n * DQ;
        k_gather<<<(int)((tot + 255) / 256), 256, 0, stream>>>(x, gam, starts, srec, out, den, n);
    } else {
        k_init_atomic<<<(n + 255) / 256, 256, 0, stream>>>(den, out, n);
        long long tot = (long long)E * DQ;
        k_edge_atomic<<<(int)((tot + 255) / 256), 256, 0, stream>>>(x, gam, esrc, edst, edge_w, out, den, E);
    }

    k_node<<<(n + 255) / 256, 256, 0, stream>>>(out, den, h_init, W, bias, n);
}